// Round 9
// baseline (304.497 us; speedup 1.0000x reference)
//
#include <hip/hip_runtime.h>
#include <hip/hip_bf16.h>

// MultiheadAttention B=4 T=2048 F=256 H=8 (head dim = F = 256).
// Harness I/O: float32. Internal: bf16 MFMA, fp32 accum.
// R23: exact R20 base (289.5us best: 2D-grid gemm_qkv, VSS=40 flash, m64 proj,
//   fused k_pre) + ONE change: flash K staged FRAGMENT-LINEAR (R16's verified
//   both-sides scatter): segment s holds K[row=l&31][chunk 2s+(l>>5)] at
//   lane-linear LDS dest; QK read = Ks[kf*512 + lane*8] -> consecutive lanes
//   read consecutive 16B, conflict-free (old l32*256 row-major read was 4-way:
//   the whole 1.09e7 conflict count; VSS=34 A/B proved V contributes ~none).

typedef __attribute__((ext_vector_type(8))) short bf16x8;    // MFMA A/B frag (4 VGPRs)
typedef __attribute__((ext_vector_type(4))) short s16x4;     // 8B store unit
typedef __attribute__((ext_vector_type(4))) float f32x4;
typedef __attribute__((ext_vector_type(16))) float f32x16;   // 32x32 MFMA C/D frag
typedef __attribute__((ext_vector_type(4))) int i32x4;       // 16B copy unit

#define MFMA16(a, b, c) __builtin_amdgcn_mfma_f32_16x16x32_bf16((a), (b), (c), 0, 0, 0)
#define MFMA32(a, b, c) __builtin_amdgcn_mfma_f32_32x32x16_bf16((a), (b), (c), 0, 0, 0)

static __device__ __forceinline__ short bf16_bits(float v) {
    __hip_bfloat16 h = __float2bfloat16(v);
    return reinterpret_cast<short&>(h);
}

static __device__ __forceinline__ unsigned pack_bf16(float lo, float hi) {
    unsigned a = (unsigned)(unsigned short)bf16_bits(lo);
    unsigned b = (unsigned)(unsigned short)bf16_bits(hi);
    return a | (b << 16);
}

static __device__ __forceinline__ void dma_lds16(const void* g, void* l) {
    __builtin_amdgcn_global_load_lds((const __attribute__((address_space(1))) unsigned int*)g,
                                     (__attribute__((address_space(3))) unsigned int*)l,
                                     16, 0, 0);
}

static __device__ __forceinline__ i32x4 cvt8(const float* __restrict__ src) {
    f32x4 a = *(const f32x4*)(src);
    f32x4 b = *(const f32x4*)(src + 4);
    union { short s[8]; i32x4 v; } u;
#pragma unroll
    for (int i = 0; i < 4; ++i) {
        u.s[i]     = bf16_bits(a[i]);
        u.s[i + 4] = bf16_bits(b[i]);
    }
    return u.v;
}

// ---- fused preprocessing: [0,1024) cvt_x | [1024,2560) qkvW transpose+permute
//      | [2560,3072) W_proj transpose ----
__global__ __launch_bounds__(256) void k_pre(const float* __restrict__ x,
                                             const float* __restrict__ W_qkv,
                                             const float* __restrict__ W_proj,
                                             __hip_bfloat16* __restrict__ Xb,
                                             __hip_bfloat16* __restrict__ WqkvT,
                                             __hip_bfloat16* __restrict__ WprojT) {
    const int id = blockIdx.x;
    if (id < 1024) {
        size_t i = ((size_t)id * 256 + threadIdx.x) * 8;
        *(i32x4*)(Xb + i) = cvt8(x + i);
        return;
    }
    __shared__ __hip_bfloat16 tile[32][33];
    const int tx = threadIdx.x & 31;
    const int ty = threadIdx.x >> 5;
    if (id < 2560) {
        // W_qkv[256,6144] -> out[n'][k], n = h*768+f*3+c -> n' = c*2048+h*256+f
        const int t = id - 1024;
        const int c0 = (t % 192) * 32, r0 = (t / 192) * 32;
#pragma unroll
        for (int j = 0; j < 4; ++j)
            tile[ty + j * 8][tx] =
                __float2bfloat16(W_qkv[(size_t)(r0 + ty + j * 8) * 6144 + c0 + tx]);
        __syncthreads();
#pragma unroll
        for (int j = 0; j < 4; ++j) {
            int n = c0 + ty + j * 8;
            int h = n / 768, rem = n - h * 768;
            int f = rem / 3, c = rem - f * 3;
            int np = c * 2048 + h * 256 + f;
            WqkvT[(size_t)np * 256 + r0 + tx] = tile[tx][ty + j * 8];
        }
    } else {
        // W_proj[2048,256] -> WprojT[256,2048]
        const int t = id - 2560;
        const int c0 = (t & 7) * 32, r0 = (t >> 3) * 32;
#pragma unroll
        for (int j = 0; j < 4; ++j)
            tile[ty + j * 8][tx] =
                __float2bfloat16(W_proj[(size_t)(r0 + ty + j * 8) * 256 + c0 + tx]);
        __syncthreads();
#pragma unroll
        for (int j = 0; j < 4; ++j)
            WprojT[(size_t)(c0 + ty + j * 8) * 2048 + r0 + tx] = tile[tx][ty + j * 8];
    }
}

// ---------------- GEMM1: qkv = x @ W_qkv + b (permuted N) ------------------------
// X[8192,256] bf16 (pre-converted), Wt[6144,256] bf16 in n' order.
// Double-buffered global_load_lds staging; counted vmcnt(4).
// Q/K: per-wave LDS transpose -> 16B vector stores of dst[bh][t][f] * 1/16.
// V: direct transposed+key-permuted 8B stores.
#define GS 32
__global__ __launch_bounds__(256) void k_gemm_qkv(const __hip_bfloat16* __restrict__ X,
                                                  const __hip_bfloat16* __restrict__ Wt,
                                                  const float* __restrict__ bias,
                                                  __hip_bfloat16* __restrict__ Q,
                                                  __hip_bfloat16* __restrict__ K,
                                                  __hip_bfloat16* __restrict__ Vt) {
    __shared__ __align__(16) short As[2][128 * GS];
    __shared__ __align__(16) short Bs[2][128 * GS];
    const int tid = threadIdx.x;
    const int m0 = blockIdx.y * 128, n0 = blockIdx.x * 128;
    const int w = tid >> 6, lane = tid & 63, l16 = lane & 15, quad = lane >> 4;
    const int wm = (w >> 1) * 64, wn = (w & 1) * 64;

    // staging geometry: chunk ci -> row=ci>>2, col=(ci&3)*8
    const int ci0 = (w * 2 + 0) * 64 + lane, ci1 = (w * 2 + 1) * 64 + lane;
    const int r0s = ci0 >> 2, c0s = (ci0 & 3) * 8;
    const int r1s = ci1 >> 2, c1s = (ci1 & 3) * 8;

    f32x4 acc[4][4];
#pragma unroll
    for (int mi = 0; mi < 4; ++mi)
#pragma unroll
        for (int ni = 0; ni < 4; ++ni) acc[mi][ni] = (f32x4){0.f, 0.f, 0.f, 0.f};

    // prologue: stage k=0 into buffer 0 (4 DMAs per wave)
    dma_lds16(X + (size_t)(m0 + r0s) * 256 + c0s, &As[0][(w * 2 + 0) * 512]);
    dma_lds16(Wt + (size_t)(n0 + r0s) * 256 + c0s, &Bs[0][(w * 2 + 0) * 512]);
    dma_lds16(X + (size_t)(m0 + r1s) * 256 + c1s, &As[0][(w * 2 + 1) * 512]);
    dma_lds16(Wt + (size_t)(n0 + r1s) * 256 + c1s, &Bs[0][(w * 2 + 1) * 512]);

    for (int it = 0; it < 8; ++it) {
        const int cur = it & 1, nxt = cur ^ 1;
        if (it < 7) {
            const int k0 = (it + 1) * 32;
            dma_lds16(X + (size_t)(m0 + r0s) * 256 + k0 + c0s, &As[nxt][(w * 2 + 0) * 512]);
            dma_lds16(Wt + (size_t)(n0 + r0s) * 256 + k0 + c0s, &Bs[nxt][(w * 2 + 0) * 512]);
            dma_lds16(X + (size_t)(m0 + r1s) * 256 + k0 + c1s, &As[nxt][(w * 2 + 1) * 512]);
            dma_lds16(Wt + (size_t)(n0 + r1s) * 256 + k0 + c1s, &Bs[nxt][(w * 2 + 1) * 512]);
            asm volatile("s_waitcnt vmcnt(4)" ::: "memory");  // tile `it` landed
        } else {
            asm volatile("s_waitcnt vmcnt(0)" ::: "memory");
        }
        __builtin_amdgcn_s_barrier();

        bf16x8 af[4], bfr[4];
#pragma unroll
        for (int mi = 0; mi < 4; ++mi)
            af[mi] = *(const bf16x8*)&As[cur][(wm + mi * 16 + l16) * GS + quad * 8];
#pragma unroll
        for (int ni = 0; ni < 4; ++ni)
            bfr[ni] = *(const bf16x8*)&Bs[cur][(wn + ni * 16 + l16) * GS + quad * 8];
#pragma unroll
        for (int mi = 0; mi < 4; ++mi)
#pragma unroll
            for (int ni = 0; ni < 4; ++ni)
                acc[mi][ni] = MFMA16(af[mi], bfr[ni], acc[mi][ni]);

        asm volatile("s_waitcnt lgkmcnt(0)" ::: "memory");  // reads done before overwrite
        __builtin_amdgcn_s_barrier();
    }

    const int c = n0 >> 11;
    if (c < 2) {
        // Q/K epilogue: per-wave LDS transpose (pad-68 rows), then 16B stores.
        __hip_bfloat16* dst = (c == 0) ? Q : K;
        const int h = ((n0 + wn) >> 8) & 7;
        const int fb = (n0 + wn) & 255;
        const int m_base = m0 + wm;
        const int b = m_base >> 11;
        short* ebuf = &As[0][0] + w * (16 * 68);   // 1088 shorts/wave, disjoint
#pragma unroll
        for (int mi = 0; mi < 4; ++mi) {
#pragma unroll
            for (int ni = 0; ni < 4; ++ni) {
                float bv = bias[h * 768 + (fb + ni * 16 + l16) * 3 + c];
#pragma unroll
                for (int r = 0; r < 4; ++r)
                    ebuf[(quad * 4 + r) * 68 + ni * 16 + l16] =
                        bf16_bits((acc[mi][ni][r] + bv) * 0.0625f);
            }
            asm volatile("s_waitcnt lgkmcnt(0)" ::: "memory");
#pragma unroll
            for (int p = 0; p < 2; ++p) {
                int row = p * 8 + (lane >> 3), cc = lane & 7;
                i32x4 v = *(const i32x4*)&ebuf[row * 68 + cc * 8];
                int t = (m_base + mi * 16 + row) & 2047;
                *(i32x4*)(dst + ((size_t)(b * 8 + h) * 2048 + t) * 256 + fb + cc * 8) = v;
            }
            asm volatile("s_waitcnt lgkmcnt(0)" ::: "memory");
        }
    } else {
        // V: Vt[bh][f][(t&~31) | pos], pos = 16(mi&1)+8(quad&1)+4(quad>>1)+r
        const int pos = ((quad & 1) << 3) | ((quad >> 1) << 2);
#pragma unroll
        for (int mi = 0; mi < 4; ++mi) {
            int m = m0 + wm + mi * 16 + quad * 4;  // r = 0
            int b = m >> 11, t = m & 2047;
            size_t tcol = (size_t)(t & ~31) + ((mi & 1) << 4) + pos;
#pragma unroll
            for (int ni = 0; ni < 4; ++ni) {
                int np = n0 + wn + ni * 16 + l16;
                int h = (np >> 8) & 7, f = np & 255;
                float bv = bias[h * 768 + f * 3 + 2];
                s16x4 v;
#pragma unroll
                for (int r = 0; r < 4; ++r) v[r] = bf16_bits(acc[mi][ni][r] + bv);
                *(s16x4*)(Vt + ((size_t)(b * 8 + h) * 256 + f) * 2048 + tcol) = v;
            }
        }
    }
}

// ---------------- flash attention (512 thr, S^T, DMA-K, dbuf, no-shfl P) ---------
// R14 structure, 1D grid + XCD remap. K staged FRAGMENT-LINEAR:
// segment s (wave w stages s = 2w, 2w+1): LDS[s*1024B + l*16B] holds
// K[row = l&31][16B chunk 2s + (l>>5)]. QK read for MFMA kf:
// Ks[kf*512 + lane*8] (shorts) -> lane-consecutive 16B, conflict-free.
// V path (VSS=40, 16B-aligned rows) and epilogue unchanged.
#define VSS 40
#define ES 40
__global__ __launch_bounds__(512) void k_flash(const __hip_bfloat16* __restrict__ Q,
                                               const __hip_bfloat16* __restrict__ K,
                                               const __hip_bfloat16* __restrict__ Vt,
                                               __hip_bfloat16* __restrict__ O) {
    __shared__ __align__(16) short Ks[2][32 * 256];
    __shared__ __align__(16) short Vs[2][256 * VSS];
    const int tid = threadIdx.x;
    const int w = tid >> 6, lane = tid & 63;
    const int l32 = lane & 31, hi = lane >> 5;

    // XCD-aware remap (index-only; verified FETCH 283->49MB)
    const int id = blockIdx.x;
    const int slot = id >> 3;                  // 0..31 within XCD
    const int bh = (id & 7) * 4 + (slot & 3);  // 4 bh per XCD
    const int q0 = (slot >> 2) * 256;          // 8 q-blocks of 256 rows

    const __hip_bfloat16* Qb = Q + (size_t)bh * 2048 * 256;
    const __hip_bfloat16* Kb = K + (size_t)bh * 2048 * 256;
    const __hip_bfloat16* Vb = Vt + (size_t)bh * 256 * 2048;

    // resident Q fragments (B-operand): lane n=q=l32, k contiguous
    bf16x8 qf[16];
    {
        const __hip_bfloat16* qrow_p = Qb + (size_t)(q0 + w * 32 + l32) * 256 + hi * 8;
#pragma unroll
        for (int kf = 0; kf < 16; ++kf) qf[kf] = *(const bf16x8*)(qrow_p + kf * 16);
    }

    f32x16 oacc[8];
#pragma unroll
    for (int nt = 0; nt < 8; ++nt)
#pragma unroll
        for (int r = 0; r < 16; ++r) oacc[nt][r] = 0.f;
    float lsum = 0.f;

    // staging geometry (512 threads)
    const int vrow = (tid >> 2);            // V rows: p*128 + (tid>>2)
    const int vcol = (tid & 3) * 8;
    // K fragment-linear source: lane l of segment s -> row l&31, chunk 2s+(l>>5)
    const int krow = l32;                   // global K row offset within tile
    // per-segment chunk base computed in loop: (2*seg + hi)*8 shorts

    // prologue: stage tile 0 into buffer 0
#pragma unroll
    for (int p = 0; p < 2; ++p) {
        int seg = w * 2 + p;
        dma_lds16(Kb + (size_t)krow * 256 + (seg * 2 + hi) * 8, &Ks[0][seg * 512]);
    }
#pragma unroll
    for (int p = 0; p < 2; ++p) {
        int row = vrow + p * 128;
        *(i32x4*)&Vs[0][row * VSS + vcol] = *(const i32x4*)(Vb + (size_t)row * 2048 + vcol);
    }
    __syncthreads();

    for (int it = 0; it < 64; ++it) {
        const int cur = it & 1, nxt = cur ^ 1;
        const bool more = it < 63;
        const int ktn = (it + 1) * 32;

        // async K DMA for next tile into alternate buffer + V prefetch to regs
        i32x4 vreg[2];
        if (more) {
#pragma unroll
            for (int p = 0; p < 2; ++p) {
                int seg = w * 2 + p;
                dma_lds16(Kb + (size_t)(ktn + krow) * 256 + (seg * 2 + hi) * 8,
                          &Ks[nxt][seg * 512]);
            }
#pragma unroll
            for (int p = 0; p < 2; ++p) {
                int row = vrow + p * 128;
                vreg[p] = *(const i32x4*)(Vb + (size_t)row * 2048 + ktn + vcol);
            }
        }

        // S^T[32key x 32q] = K * Q^T : 16 MFMA over f; frag-linear reads
        f32x16 s;
#pragma unroll
        for (int r = 0; r < 16; ++r) s[r] = 0.f;
#pragma unroll
        for (int kf = 0; kf < 16; ++kf) {
            bf16x8 kfr = *(const bf16x8*)&Ks[cur][kf * 512 + lane * 8];
            s = MFMA32(kfr, qf[kf], s);
        }

        // per-kk: P = exp(S) packed straight into the B-frag, then PV.
#pragma unroll
        for (int kk = 0; kk < 2; ++kk) {
            unsigned ch[4];
#pragma unroll
            for (int c = 0; c < 4; ++c) {
                float e0 = __expf(s[8 * kk + 2 * c]);
                float e1 = __expf(s[8 * kk + 2 * c + 1]);
                lsum += e0 + e1;
                ch[c] = pack_bf16(e0, e1);
            }
            union { i32x4 i; bf16x8 v; } pf;
            pf.i = (i32x4){(int)ch[0], (int)ch[1], (int)ch[2], (int)ch[3]};

#pragma unroll
            for (int nt = 0; nt < 8; ++nt) {
                bf16x8 vf = *(const bf16x8*)&Vs[cur][(nt * 32 + l32) * VSS + kk * 16 + hi * 8];
                oacc[nt] = MFMA32(vf, pf.v, oacc[nt]);
            }
        }

        if (more) {
#pragma unroll
            for (int p = 0; p < 2; ++p) {
                int row = vrow + p * 128;
                *(i32x4*)&Vs[nxt][row * VSS + vcol] = vreg[p];
            }
        }
        __syncthreads();
    }

    // total row sum: own 16 keys + partner hi-half's 16 keys
    lsum += __shfl_xor(lsum, 32);
    const float inv = 1.f / lsum;

    // epilogue: O^T -> [t][hf] via per-wave LDS transpose (reuse Ks region)
    short* ebuf = &Ks[0][0] + w * (32 * ES);
    const int b = bh >> 3, hh = bh & 7;
#pragma unroll
    for (int nt = 0; nt < 8; ++nt) {
#pragma unroll
        for (int r = 0; r < 16; ++r) {
            int fl = (r & 3) + 8 * (r >> 2) + 4 * hi;
            ebuf[l32 * ES + fl] = bf16_bits(oacc[nt][r] * inv);
        }
        asm volatile("s_waitcnt lgkmcnt(0)" ::: "memory");
#pragma unroll
        for (int p = 0; p < 2; ++p) {
            i32x4 v = *(const i32x4*)&ebuf[(lane >> 1) * ES + (lane & 1) * 8 + p * 16];
            int t = q0 + w * 32 + (lane >> 1);
            __hip_bfloat16* dst =
                O + ((size_t)(b * 2048 + t) * 2048 + hh * 256 + nt * 32 + (lane & 1) * 8 + p * 16);
            *(i32x4*)dst = v;
        }
        asm volatile("s_waitcnt lgkmcnt(0)" ::: "memory");
    }
}

// ---------------- GEMM3: out = attn @ W_proj + b_proj (f32 out) ------------------
// m-tile 64, grid 512 linear (2 blocks/CU). XCD remap: the 4 n-blocks of one
// m-panel run on the SAME XCD. Double-buffered staging, counted vmcnt(2).
__global__ __launch_bounds__(256) void k_gemm_proj(const __hip_bfloat16* __restrict__ A,
                                                   const __hip_bfloat16* __restrict__ Wt,
                                                   const float* __restrict__ bias,
                                                   float* __restrict__ Out) {
    __shared__ __align__(16) short As[2][64 * GS];
    __shared__ __align__(16) short Bs[2][64 * GS];
    const int tid = threadIdx.x;
    const int id = blockIdx.x;
    const int slot = id >> 3;                       // 0..63 within XCD
    const int n0 = (slot & 3) * 64;                 // 4 n-blocks consecutive on one XCD
    const int m0 = ((id & 7) + 8 * (slot >> 2)) * 64;
    const int w = tid >> 6, lane = tid & 63, l16 = lane & 15, quad = lane >> 4;
    const int wm = w * 16;

    // staging: chunk = tid; row = tid>>2 (0..63), col = (tid&3)*8
    const int rS = tid >> 2, cS = (tid & 3) * 8;

    f32x4 acc[4];
#pragma unroll
    for (int ni = 0; ni < 4; ++ni) acc[ni] = (f32x4){0.f, 0.f, 0.f, 0.f};

    // prologue: stage k=0 into buffer 0 (2 DMAs per wave)
    dma_lds16(A + (size_t)(m0 + rS) * 2048 + cS, &As[0][w * 512]);
    dma_lds16(Wt + (size_t)(n0 + rS) * 2048 + cS, &Bs[0][w * 512]);

    for (int it = 0; it < 64; ++it) {
        const int cur = it & 1, nxt = cur ^ 1;
        if (it < 63) {
            const int k0 = (it + 1) * 32;
            dma_lds16(A + (size_t)(m0 + rS) * 2048 + k0 + cS, &As[nxt][w * 512]);
            dma_lds16(Wt + (size_t)(n0 + rS) * 2048 + k0 + cS, &Bs[nxt][w * 512]);
            asm volatile("s_waitcnt vmcnt(2)" ::: "memory");  // tile `it` landed
        } else {
            asm volatile("s_waitcnt vmcnt(0)" ::: "memory");
        }
        __builtin_amdgcn_s_barrier();

        bf16x8 af = *(const bf16x8*)&As[cur][(wm + l16) * GS + quad * 8];
        bf16x8 bfr[4];
#pragma unroll
        for (int ni = 0; ni < 4; ++ni)
            bfr[ni] = *(const bf16x8*)&Bs[cur][(ni * 16 + l16) * GS + quad * 8];
#pragma unroll
        for (int ni = 0; ni < 4; ++ni)
            acc[ni] = MFMA16(af, bfr[ni], acc[ni]);

        asm volatile("s_waitcnt lgkmcnt(0)" ::: "memory");
        __builtin_amdgcn_s_barrier();
    }

#pragma unroll
    for (int ni = 0; ni < 4; ++ni) {
        int n = n0 + ni * 16 + l16;
        float bv = bias[n];
#pragma unroll
        for (int r = 0; r < 4; ++r) {
            int m = m0 + wm + quad * 4 + r;
            Out[(size_t)m * 256 + n] = acc[ni][r] + bv;
        }
    }
}

// ---------------- launch ---------------------------------------------------------
extern "C" void kernel_launch(void* const* d_in, const int* in_sizes, int n_in,
                              void* d_out, int out_size, void* d_ws, size_t ws_size,
                              hipStream_t stream) {
    const float* x      = (const float*)d_in[0];  // [4,2048,256]
    const float* W_qkv  = (const float*)d_in[1];  // [256,6144]
    const float* b_qkv  = (const float*)d_in[2];  // [6144]
    const float* W_proj = (const float*)d_in[3];  // [2048,256]
    const float* b_proj = (const float*)d_in[4];  // [256]
    float* out = (float*)d_out;                   // [4,2048,256]

    const size_t E = 32ull * 2048 * 256;
    __hip_bfloat16* Qb     = (__hip_bfloat16*)d_ws;
    __hip_bfloat16* Kb     = Qb + E;
    __hip_bfloat16* Vt     = Kb + E;
    __hip_bfloat16* attn   = Vt + E;
    __hip_bfloat16* WqkvT  = attn + E;           // 6144*256
    __hip_bfloat16* WprojT = WqkvT + 6144 * 256; // 256*2048
    // Xb aliases attn: gemm_qkv consumes it before k_flash overwrites attn.
    __hip_bfloat16* Xb     = attn;               // 8192*256 bf16 (4 MB of 32 MB)

    k_pre<<<dim3(3072), 256, 0, stream>>>(x, W_qkv, W_proj, Xb, WqkvT, WprojT);
    k_gemm_qkv<<<dim3(48, 64), 256, 0, stream>>>(Xb, WqkvT, b_qkv, Qb, Kb, Vt);
    k_flash<<<dim3(256), 512, 0, stream>>>(Qb, Kb, Vt, attn);
    k_gemm_proj<<<dim3(512), 256, 0, stream>>>(attn, WprojT, b_proj, out);
}

// Round 10
// 291.018 us; speedup vs baseline: 1.0463x; 1.0463x over previous
//
#include <hip/hip_runtime.h>
#include <hip/hip_bf16.h>

// MultiheadAttention B=4 T=2048 F=256 H=8 (head dim = F = 256).
// Harness I/O: float32. Internal: bf16 MFMA, fp32 accum.
// R24 = exact R20 (measured best, 289.5us). Final configuration.
//   - k_pre: fused cvt_x + W_qkv transpose/permute + W_proj transpose.
//   - k_gemm_qkv: 128x128 tile, dbuf global_load_lds + counted vmcnt(4),
//     Q/K per-wave LDS-transpose epilogue, V transposed+key-permuted stores.
//   - k_flash: R14 8-wave structure + XCD remap (161-163us). Conflict fixes
//     proven non-binding (R16/R22/R23); structure is dependency-bound.
//   - k_gemm_proj: m64 tile, 512 blocks (2/CU), XCD remap, dbuf + vmcnt(2).

typedef __attribute__((ext_vector_type(8))) short bf16x8;    // MFMA A/B frag (4 VGPRs)
typedef __attribute__((ext_vector_type(4))) short s16x4;     // 8B store unit
typedef __attribute__((ext_vector_type(4))) float f32x4;
typedef __attribute__((ext_vector_type(16))) float f32x16;   // 32x32 MFMA C/D frag
typedef __attribute__((ext_vector_type(4))) int i32x4;       // 16B copy unit

#define MFMA16(a, b, c) __builtin_amdgcn_mfma_f32_16x16x32_bf16((a), (b), (c), 0, 0, 0)
#define MFMA32(a, b, c) __builtin_amdgcn_mfma_f32_32x32x16_bf16((a), (b), (c), 0, 0, 0)

static __device__ __forceinline__ short bf16_bits(float v) {
    __hip_bfloat16 h = __float2bfloat16(v);
    return reinterpret_cast<short&>(h);
}

static __device__ __forceinline__ unsigned pack_bf16(float lo, float hi) {
    unsigned a = (unsigned)(unsigned short)bf16_bits(lo);
    unsigned b = (unsigned)(unsigned short)bf16_bits(hi);
    return a | (b << 16);
}

static __device__ __forceinline__ void dma_lds16(const void* g, void* l) {
    __builtin_amdgcn_global_load_lds((const __attribute__((address_space(1))) unsigned int*)g,
                                     (__attribute__((address_space(3))) unsigned int*)l,
                                     16, 0, 0);
}

static __device__ __forceinline__ i32x4 cvt8(const float* __restrict__ src) {
    f32x4 a = *(const f32x4*)(src);
    f32x4 b = *(const f32x4*)(src + 4);
    union { short s[8]; i32x4 v; } u;
#pragma unroll
    for (int i = 0; i < 4; ++i) {
        u.s[i]     = bf16_bits(a[i]);
        u.s[i + 4] = bf16_bits(b[i]);
    }
    return u.v;
}

// ---- fused preprocessing: [0,1024) cvt_x | [1024,2560) qkvW transpose+permute
//      | [2560,3072) W_proj transpose ----
__global__ __launch_bounds__(256) void k_pre(const float* __restrict__ x,
                                             const float* __restrict__ W_qkv,
                                             const float* __restrict__ W_proj,
                                             __hip_bfloat16* __restrict__ Xb,
                                             __hip_bfloat16* __restrict__ WqkvT,
                                             __hip_bfloat16* __restrict__ WprojT) {
    const int id = blockIdx.x;
    if (id < 1024) {
        size_t i = ((size_t)id * 256 + threadIdx.x) * 8;
        *(i32x4*)(Xb + i) = cvt8(x + i);
        return;
    }
    __shared__ __hip_bfloat16 tile[32][33];
    const int tx = threadIdx.x & 31;
    const int ty = threadIdx.x >> 5;
    if (id < 2560) {
        // W_qkv[256,6144] -> out[n'][k], n = h*768+f*3+c -> n' = c*2048+h*256+f
        const int t = id - 1024;
        const int c0 = (t % 192) * 32, r0 = (t / 192) * 32;
#pragma unroll
        for (int j = 0; j < 4; ++j)
            tile[ty + j * 8][tx] =
                __float2bfloat16(W_qkv[(size_t)(r0 + ty + j * 8) * 6144 + c0 + tx]);
        __syncthreads();
#pragma unroll
        for (int j = 0; j < 4; ++j) {
            int n = c0 + ty + j * 8;
            int h = n / 768, rem = n - h * 768;
            int f = rem / 3, c = rem - f * 3;
            int np = c * 2048 + h * 256 + f;
            WqkvT[(size_t)np * 256 + r0 + tx] = tile[tx][ty + j * 8];
        }
    } else {
        // W_proj[2048,256] -> WprojT[256,2048]
        const int t = id - 2560;
        const int c0 = (t & 7) * 32, r0 = (t >> 3) * 32;
#pragma unroll
        for (int j = 0; j < 4; ++j)
            tile[ty + j * 8][tx] =
                __float2bfloat16(W_proj[(size_t)(r0 + ty + j * 8) * 256 + c0 + tx]);
        __syncthreads();
#pragma unroll
        for (int j = 0; j < 4; ++j)
            WprojT[(size_t)(c0 + ty + j * 8) * 2048 + r0 + tx] = tile[tx][ty + j * 8];
    }
}

// ---------------- GEMM1: qkv = x @ W_qkv + b (permuted N) ------------------------
// X[8192,256] bf16 (pre-converted), Wt[6144,256] bf16 in n' order.
// Double-buffered global_load_lds staging; counted vmcnt(4).
// Q/K: per-wave LDS transpose -> 16B vector stores of dst[bh][t][f] * 1/16.
// V: direct transposed+key-permuted 8B stores.
#define GS 32
__global__ __launch_bounds__(256) void k_gemm_qkv(const __hip_bfloat16* __restrict__ X,
                                                  const __hip_bfloat16* __restrict__ Wt,
                                                  const float* __restrict__ bias,
                                                  __hip_bfloat16* __restrict__ Q,
                                                  __hip_bfloat16* __restrict__ K,
                                                  __hip_bfloat16* __restrict__ Vt) {
    __shared__ __align__(16) short As[2][128 * GS];
    __shared__ __align__(16) short Bs[2][128 * GS];
    const int tid = threadIdx.x;
    const int m0 = blockIdx.y * 128, n0 = blockIdx.x * 128;
    const int w = tid >> 6, lane = tid & 63, l16 = lane & 15, quad = lane >> 4;
    const int wm = (w >> 1) * 64, wn = (w & 1) * 64;

    // staging geometry: chunk ci -> row=ci>>2, col=(ci&3)*8
    const int ci0 = (w * 2 + 0) * 64 + lane, ci1 = (w * 2 + 1) * 64 + lane;
    const int r0s = ci0 >> 2, c0s = (ci0 & 3) * 8;
    const int r1s = ci1 >> 2, c1s = (ci1 & 3) * 8;

    f32x4 acc[4][4];
#pragma unroll
    for (int mi = 0; mi < 4; ++mi)
#pragma unroll
        for (int ni = 0; ni < 4; ++ni) acc[mi][ni] = (f32x4){0.f, 0.f, 0.f, 0.f};

    // prologue: stage k=0 into buffer 0 (4 DMAs per wave)
    dma_lds16(X + (size_t)(m0 + r0s) * 256 + c0s, &As[0][(w * 2 + 0) * 512]);
    dma_lds16(Wt + (size_t)(n0 + r0s) * 256 + c0s, &Bs[0][(w * 2 + 0) * 512]);
    dma_lds16(X + (size_t)(m0 + r1s) * 256 + c1s, &As[0][(w * 2 + 1) * 512]);
    dma_lds16(Wt + (size_t)(n0 + r1s) * 256 + c1s, &Bs[0][(w * 2 + 1) * 512]);

    for (int it = 0; it < 8; ++it) {
        const int cur = it & 1, nxt = cur ^ 1;
        if (it < 7) {
            const int k0 = (it + 1) * 32;
            dma_lds16(X + (size_t)(m0 + r0s) * 256 + k0 + c0s, &As[nxt][(w * 2 + 0) * 512]);
            dma_lds16(Wt + (size_t)(n0 + r0s) * 256 + k0 + c0s, &Bs[nxt][(w * 2 + 0) * 512]);
            dma_lds16(X + (size_t)(m0 + r1s) * 256 + k0 + c1s, &As[nxt][(w * 2 + 1) * 512]);
            dma_lds16(Wt + (size_t)(n0 + r1s) * 256 + k0 + c1s, &Bs[nxt][(w * 2 + 1) * 512]);
            asm volatile("s_waitcnt vmcnt(4)" ::: "memory");  // tile `it` landed
        } else {
            asm volatile("s_waitcnt vmcnt(0)" ::: "memory");
        }
        __builtin_amdgcn_s_barrier();

        bf16x8 af[4], bfr[4];
#pragma unroll
        for (int mi = 0; mi < 4; ++mi)
            af[mi] = *(const bf16x8*)&As[cur][(wm + mi * 16 + l16) * GS + quad * 8];
#pragma unroll
        for (int ni = 0; ni < 4; ++ni)
            bfr[ni] = *(const bf16x8*)&Bs[cur][(wn + ni * 16 + l16) * GS + quad * 8];
#pragma unroll
        for (int mi = 0; mi < 4; ++mi)
#pragma unroll
            for (int ni = 0; ni < 4; ++ni)
                acc[mi][ni] = MFMA16(af[mi], bfr[ni], acc[mi][ni]);

        asm volatile("s_waitcnt lgkmcnt(0)" ::: "memory");  // reads done before overwrite
        __builtin_amdgcn_s_barrier();
    }

    const int c = n0 >> 11;
    if (c < 2) {
        // Q/K epilogue: per-wave LDS transpose (pad-68 rows), then 16B stores.
        __hip_bfloat16* dst = (c == 0) ? Q : K;
        const int h = ((n0 + wn) >> 8) & 7;
        const int fb = (n0 + wn) & 255;
        const int m_base = m0 + wm;
        const int b = m_base >> 11;
        short* ebuf = &As[0][0] + w * (16 * 68);   // 1088 shorts/wave, disjoint
#pragma unroll
        for (int mi = 0; mi < 4; ++mi) {
#pragma unroll
            for (int ni = 0; ni < 4; ++ni) {
                float bv = bias[h * 768 + (fb + ni * 16 + l16) * 3 + c];
#pragma unroll
                for (int r = 0; r < 4; ++r)
                    ebuf[(quad * 4 + r) * 68 + ni * 16 + l16] =
                        bf16_bits((acc[mi][ni][r] + bv) * 0.0625f);
            }
            asm volatile("s_waitcnt lgkmcnt(0)" ::: "memory");
#pragma unroll
            for (int p = 0; p < 2; ++p) {
                int row = p * 8 + (lane >> 3), cc = lane & 7;
                i32x4 v = *(const i32x4*)&ebuf[row * 68 + cc * 8];
                int t = (m_base + mi * 16 + row) & 2047;
                *(i32x4*)(dst + ((size_t)(b * 8 + h) * 2048 + t) * 256 + fb + cc * 8) = v;
            }
            asm volatile("s_waitcnt lgkmcnt(0)" ::: "memory");
        }
    } else {
        // V: Vt[bh][f][(t&~31) | pos], pos = 16(mi&1)+8(quad&1)+4(quad>>1)+r
        const int pos = ((quad & 1) << 3) | ((quad >> 1) << 2);
#pragma unroll
        for (int mi = 0; mi < 4; ++mi) {
            int m = m0 + wm + mi * 16 + quad * 4;  // r = 0
            int b = m >> 11, t = m & 2047;
            size_t tcol = (size_t)(t & ~31) + ((mi & 1) << 4) + pos;
#pragma unroll
            for (int ni = 0; ni < 4; ++ni) {
                int np = n0 + wn + ni * 16 + l16;
                int h = (np >> 8) & 7, f = np & 255;
                float bv = bias[h * 768 + f * 3 + 2];
                s16x4 v;
#pragma unroll
                for (int r = 0; r < 4; ++r) v[r] = bf16_bits(acc[mi][ni][r] + bv);
                *(s16x4*)(Vt + ((size_t)(b * 8 + h) * 256 + f) * 2048 + tcol) = v;
            }
        }
    }
}

// ---------------- flash attention (512 thr, S^T, DMA-K, dbuf, no-shfl P) ---------
// R14 structure (measured best), 1D grid + XCD remap.
// grid: 256 blocks; xcd=id&7 owns bh in [xcd*4, xcd*4+4); 8 q-blocks of 256.
// Block 512 = 8 waves; wave w owns 32 q-rows (full F=256).
// S^T = K*Q^T: lane owns q=l32 and keys (r&3)+8*(r>>2)+4hi. V stored key-permuted,
// so pf[kk] = pack(exp(s[8kk..8kk+7])) with NO lane exchange.
#define VSS 40
#define ES 40
__global__ __launch_bounds__(512) void k_flash(const __hip_bfloat16* __restrict__ Q,
                                               const __hip_bfloat16* __restrict__ K,
                                               const __hip_bfloat16* __restrict__ Vt,
                                               __hip_bfloat16* __restrict__ O) {
    __shared__ __align__(16) short Ks[2][32 * 256];
    __shared__ __align__(16) short Vs[2][256 * VSS];
    const int tid = threadIdx.x;
    const int w = tid >> 6, lane = tid & 63;
    const int l32 = lane & 31, hi = lane >> 5;

    // XCD-aware remap (index-only; verified FETCH 283->51MB)
    const int id = blockIdx.x;
    const int slot = id >> 3;                  // 0..31 within XCD
    const int bh = (id & 7) * 4 + (slot & 3);  // 4 bh per XCD
    const int q0 = (slot >> 2) * 256;          // 8 q-blocks of 256 rows

    const __hip_bfloat16* Qb = Q + (size_t)bh * 2048 * 256;
    const __hip_bfloat16* Kb = K + (size_t)bh * 2048 * 256;
    const __hip_bfloat16* Vb = Vt + (size_t)bh * 256 * 2048;

    // resident Q fragments (B-operand): lane n=q=l32, k contiguous
    bf16x8 qf[16];
    {
        const __hip_bfloat16* qrow_p = Qb + (size_t)(q0 + w * 32 + l32) * 256 + hi * 8;
#pragma unroll
        for (int kf = 0; kf < 16; ++kf) qf[kf] = *(const bf16x8*)(qrow_p + kf * 16);
    }

    f32x16 oacc[8];
#pragma unroll
    for (int nt = 0; nt < 8; ++nt)
#pragma unroll
        for (int r = 0; r < 16; ++r) oacc[nt][r] = 0.f;
    float lsum = 0.f;

    // staging geometry (512 threads)
    const int vrow = (tid >> 2);            // V rows: p*128 + (tid>>2)
    const int vcol = (tid & 3) * 8;

    // prologue: stage tile 0 into buffer 0
#pragma unroll
    for (int p = 0; p < 2; ++p) {
        int seg = w * 2 + p;
        int r = 2 * seg + hi;
        int clog = l32 ^ (r & 7);
        dma_lds16(Kb + (size_t)r * 256 + clog * 8, &Ks[0][seg * 512]);
    }
#pragma unroll
    for (int p = 0; p < 2; ++p) {
        int row = vrow + p * 128;
        *(i32x4*)&Vs[0][row * VSS + vcol] = *(const i32x4*)(Vb + (size_t)row * 2048 + vcol);
    }
    __syncthreads();

    const int s7 = l32 & 7;
    for (int it = 0; it < 64; ++it) {
        const int cur = it & 1, nxt = cur ^ 1;
        const bool more = it < 63;
        const int ktn = (it + 1) * 32;

        // async K DMA for next tile into alternate buffer + V prefetch to regs
        i32x4 vreg[2];
        if (more) {
#pragma unroll
            for (int p = 0; p < 2; ++p) {
                int seg = w * 2 + p;
                int r = 2 * seg + hi;
                int clog = l32 ^ (r & 7);
                dma_lds16(Kb + (size_t)(ktn + r) * 256 + clog * 8, &Ks[nxt][seg * 512]);
            }
#pragma unroll
            for (int p = 0; p < 2; ++p) {
                int row = vrow + p * 128;
                vreg[p] = *(const i32x4*)(Vb + (size_t)row * 2048 + ktn + vcol);
            }
        }

        // S^T[32key x 32q] = K * Q^T : 16 MFMA over f
        f32x16 s;
#pragma unroll
        for (int r = 0; r < 16; ++r) s[r] = 0.f;
        const short* ksb = &Ks[cur][l32 * 256];
#pragma unroll
        for (int kf = 0; kf < 16; ++kf) {
            int g = kf * 2 + hi;
            bf16x8 kfr = *(const bf16x8*)&ksb[((g ^ s7) * 8)];
            s = MFMA32(kfr, qf[kf], s);
        }

        // per-kk: P = exp(S) packed straight into the B-frag, then PV.
#pragma unroll
        for (int kk = 0; kk < 2; ++kk) {
            unsigned ch[4];
#pragma unroll
            for (int c = 0; c < 4; ++c) {
                float e0 = __expf(s[8 * kk + 2 * c]);
                float e1 = __expf(s[8 * kk + 2 * c + 1]);
                lsum += e0 + e1;
                ch[c] = pack_bf16(e0, e1);
            }
            union { i32x4 i; bf16x8 v; } pf;
            pf.i = (i32x4){(int)ch[0], (int)ch[1], (int)ch[2], (int)ch[3]};

#pragma unroll
            for (int nt = 0; nt < 8; ++nt) {
                bf16x8 vf = *(const bf16x8*)&Vs[cur][(nt * 32 + l32) * VSS + kk * 16 + hi * 8];
                oacc[nt] = MFMA32(vf, pf.v, oacc[nt]);
            }
        }

        if (more) {
#pragma unroll
            for (int p = 0; p < 2; ++p) {
                int row = vrow + p * 128;
                *(i32x4*)&Vs[nxt][row * VSS + vcol] = vreg[p];
            }
        }
        __syncthreads();
    }

    // total row sum: own 16 keys + partner hi-half's 16 keys
    lsum += __shfl_xor(lsum, 32);
    const float inv = 1.f / lsum;

    // epilogue: O^T -> [t][hf] via per-wave LDS transpose (reuse Ks region)
    short* ebuf = &Ks[0][0] + w * (32 * ES);
    const int b = bh >> 3, hh = bh & 7;
#pragma unroll
    for (int nt = 0; nt < 8; ++nt) {
#pragma unroll
        for (int r = 0; r < 16; ++r) {
            int fl = (r & 3) + 8 * (r >> 2) + 4 * hi;
            ebuf[l32 * ES + fl] = bf16_bits(oacc[nt][r] * inv);
        }
        asm volatile("s_waitcnt lgkmcnt(0)" ::: "memory");
#pragma unroll
        for (int p = 0; p < 2; ++p) {
            i32x4 v = *(const i32x4*)&ebuf[(lane >> 1) * ES + (lane & 1) * 8 + p * 16];
            int t = q0 + w * 32 + (lane >> 1);
            __hip_bfloat16* dst =
                O + ((size_t)(b * 2048 + t) * 2048 + hh * 256 + nt * 32 + (lane & 1) * 8 + p * 16);
            *(i32x4*)dst = v;
        }
        asm volatile("s_waitcnt lgkmcnt(0)" ::: "memory");
    }
}

// ---------------- GEMM3: out = attn @ W_proj + b_proj (f32 out) ------------------
// m-tile 64, grid 512 linear (2 blocks/CU). XCD remap: the 4 n-blocks of one
// m-panel run on the SAME XCD. Double-buffered staging, counted vmcnt(2).
__global__ __launch_bounds__(256) void k_gemm_proj(const __hip_bfloat16* __restrict__ A,
                                                   const __hip_bfloat16* __restrict__ Wt,
                                                   const float* __restrict__ bias,
                                                   float* __restrict__ Out) {
    __shared__ __align__(16) short As[2][64 * GS];
    __shared__ __align__(16) short Bs[2][64 * GS];
    const int tid = threadIdx.x;
    const int id = blockIdx.x;
    const int slot = id >> 3;                       // 0..63 within XCD
    const int n0 = (slot & 3) * 64;                 // 4 n-blocks consecutive on one XCD
    const int m0 = ((id & 7) + 8 * (slot >> 2)) * 64;
    const int w = tid >> 6, lane = tid & 63, l16 = lane & 15, quad = lane >> 4;
    const int wm = w * 16;

    // staging: chunk = tid; row = tid>>2 (0..63), col = (tid&3)*8
    const int rS = tid >> 2, cS = (tid & 3) * 8;

    f32x4 acc[4];
#pragma unroll
    for (int ni = 0; ni < 4; ++ni) acc[ni] = (f32x4){0.f, 0.f, 0.f, 0.f};

    // prologue: stage k=0 into buffer 0 (2 DMAs per wave)
    dma_lds16(A + (size_t)(m0 + rS) * 2048 + cS, &As[0][w * 512]);
    dma_lds16(Wt + (size_t)(n0 + rS) * 2048 + cS, &Bs[0][w * 512]);

    for (int it = 0; it < 64; ++it) {
        const int cur = it & 1, nxt = cur ^ 1;
        if (it < 63) {
            const int k0 = (it + 1) * 32;
            dma_lds16(A + (size_t)(m0 + rS) * 2048 + k0 + cS, &As[nxt][w * 512]);
            dma_lds16(Wt + (size_t)(n0 + rS) * 2048 + k0 + cS, &Bs[nxt][w * 512]);
            asm volatile("s_waitcnt vmcnt(2)" ::: "memory");  // tile `it` landed
        } else {
            asm volatile("s_waitcnt vmcnt(0)" ::: "memory");
        }
        __builtin_amdgcn_s_barrier();

        bf16x8 af = *(const bf16x8*)&As[cur][(wm + l16) * GS + quad * 8];
        bf16x8 bfr[4];
#pragma unroll
        for (int ni = 0; ni < 4; ++ni)
            bfr[ni] = *(const bf16x8*)&Bs[cur][(ni * 16 + l16) * GS + quad * 8];
#pragma unroll
        for (int ni = 0; ni < 4; ++ni)
            acc[ni] = MFMA16(af, bfr[ni], acc[ni]);

        asm volatile("s_waitcnt lgkmcnt(0)" ::: "memory");
        __builtin_amdgcn_s_barrier();
    }

#pragma unroll
    for (int ni = 0; ni < 4; ++ni) {
        int n = n0 + ni * 16 + l16;
        float bv = bias[n];
#pragma unroll
        for (int r = 0; r < 4; ++r) {
            int m = m0 + wm + quad * 4 + r;
            Out[(size_t)m * 256 + n] = acc[ni][r] + bv;
        }
    }
}

// ---------------- launch ---------------------------------------------------------
extern "C" void kernel_launch(void* const* d_in, const int* in_sizes, int n_in,
                              void* d_out, int out_size, void* d_ws, size_t ws_size,
                              hipStream_t stream) {
    const float* x      = (const float*)d_in[0];  // [4,2048,256]
    const float* W_qkv  = (const float*)d_in[1];  // [256,6144]
    const float* b_qkv  = (const float*)d_in[2];  // [6144]
    const float* W_proj = (const float*)d_in[3];  // [2048,256]
    const float* b_proj = (const float*)d_in[4];  // [256]
    float* out = (float*)d_out;                   // [4,2048,256]

    const size_t E = 32ull * 2048 * 256;
    __hip_bfloat16* Qb     = (__hip_bfloat16*)d_ws;
    __hip_bfloat16* Kb     = Qb + E;
    __hip_bfloat16* Vt     = Kb + E;
    __hip_bfloat16* attn   = Vt + E;
    __hip_bfloat16* WqkvT  = attn + E;           // 6144*256
    __hip_bfloat16* WprojT = WqkvT + 6144 * 256; // 256*2048
    // Xb aliases attn: gemm_qkv consumes it before k_flash overwrites attn.
    __hip_bfloat16* Xb     = attn;               // 8192*256 bf16 (4 MB of 32 MB)

    k_pre<<<dim3(3072), 256, 0, stream>>>(x, W_qkv, W_proj, Xb, WqkvT, WprojT);
    k_gemm_qkv<<<dim3(48, 64), 256, 0, stream>>>(Xb, WqkvT, b_qkv, Qb, Kb, Vt);
    k_flash<<<dim3(256), 512, 0, stream>>>(Qb, Kb, Vt, attn);
    k_gemm_proj<<<dim3(512), 256, 0, stream>>>(attn, WprojT, b_proj, out);
}

// Round 11
// 289.472 us; speedup vs baseline: 1.0519x; 1.0053x over previous
//
#include <hip/hip_runtime.h>
#include <hip/hip_bf16.h>

// MultiheadAttention B=4 T=2048 F=256 H=8 (head dim = F = 256).
// Harness I/O: float32. Internal: bf16 MFMA, fp32 accum.
// R25 = R24/R20 base (confirmed best, 289.5-291.0us) + ONE change:
//   k_flash: s_setprio(1) around the QK and PV MFMA clusters. Never tested on
//   the 8-wave structure (R15 bundled it into the 4-wave rewrite; R17's
//   removal A/B showed it was worth ~11us there). 8 waves drift across
//   QK/softmax/PV phases within the iter body -> role diversity for the CU
//   scheduler to arbitrate (m191 mechanism). Register-neutral, index-free.
//   Everything else byte-identical to R24.

typedef __attribute__((ext_vector_type(8))) short bf16x8;    // MFMA A/B frag (4 VGPRs)
typedef __attribute__((ext_vector_type(4))) short s16x4;     // 8B store unit
typedef __attribute__((ext_vector_type(4))) float f32x4;
typedef __attribute__((ext_vector_type(16))) float f32x16;   // 32x32 MFMA C/D frag
typedef __attribute__((ext_vector_type(4))) int i32x4;       // 16B copy unit

#define MFMA16(a, b, c) __builtin_amdgcn_mfma_f32_16x16x32_bf16((a), (b), (c), 0, 0, 0)
#define MFMA32(a, b, c) __builtin_amdgcn_mfma_f32_32x32x16_bf16((a), (b), (c), 0, 0, 0)

static __device__ __forceinline__ short bf16_bits(float v) {
    __hip_bfloat16 h = __float2bfloat16(v);
    return reinterpret_cast<short&>(h);
}

static __device__ __forceinline__ unsigned pack_bf16(float lo, float hi) {
    unsigned a = (unsigned)(unsigned short)bf16_bits(lo);
    unsigned b = (unsigned)(unsigned short)bf16_bits(hi);
    return a | (b << 16);
}

static __device__ __forceinline__ void dma_lds16(const void* g, void* l) {
    __builtin_amdgcn_global_load_lds((const __attribute__((address_space(1))) unsigned int*)g,
                                     (__attribute__((address_space(3))) unsigned int*)l,
                                     16, 0, 0);
}

static __device__ __forceinline__ i32x4 cvt8(const float* __restrict__ src) {
    f32x4 a = *(const f32x4*)(src);
    f32x4 b = *(const f32x4*)(src + 4);
    union { short s[8]; i32x4 v; } u;
#pragma unroll
    for (int i = 0; i < 4; ++i) {
        u.s[i]     = bf16_bits(a[i]);
        u.s[i + 4] = bf16_bits(b[i]);
    }
    return u.v;
}

// ---- fused preprocessing: [0,1024) cvt_x | [1024,2560) qkvW transpose+permute
//      | [2560,3072) W_proj transpose ----
__global__ __launch_bounds__(256) void k_pre(const float* __restrict__ x,
                                             const float* __restrict__ W_qkv,
                                             const float* __restrict__ W_proj,
                                             __hip_bfloat16* __restrict__ Xb,
                                             __hip_bfloat16* __restrict__ WqkvT,
                                             __hip_bfloat16* __restrict__ WprojT) {
    const int id = blockIdx.x;
    if (id < 1024) {
        size_t i = ((size_t)id * 256 + threadIdx.x) * 8;
        *(i32x4*)(Xb + i) = cvt8(x + i);
        return;
    }
    __shared__ __hip_bfloat16 tile[32][33];
    const int tx = threadIdx.x & 31;
    const int ty = threadIdx.x >> 5;
    if (id < 2560) {
        // W_qkv[256,6144] -> out[n'][k], n = h*768+f*3+c -> n' = c*2048+h*256+f
        const int t = id - 1024;
        const int c0 = (t % 192) * 32, r0 = (t / 192) * 32;
#pragma unroll
        for (int j = 0; j < 4; ++j)
            tile[ty + j * 8][tx] =
                __float2bfloat16(W_qkv[(size_t)(r0 + ty + j * 8) * 6144 + c0 + tx]);
        __syncthreads();
#pragma unroll
        for (int j = 0; j < 4; ++j) {
            int n = c0 + ty + j * 8;
            int h = n / 768, rem = n - h * 768;
            int f = rem / 3, c = rem - f * 3;
            int np = c * 2048 + h * 256 + f;
            WqkvT[(size_t)np * 256 + r0 + tx] = tile[tx][ty + j * 8];
        }
    } else {
        // W_proj[2048,256] -> WprojT[256,2048]
        const int t = id - 2560;
        const int c0 = (t & 7) * 32, r0 = (t >> 3) * 32;
#pragma unroll
        for (int j = 0; j < 4; ++j)
            tile[ty + j * 8][tx] =
                __float2bfloat16(W_proj[(size_t)(r0 + ty + j * 8) * 256 + c0 + tx]);
        __syncthreads();
#pragma unroll
        for (int j = 0; j < 4; ++j)
            WprojT[(size_t)(c0 + ty + j * 8) * 2048 + r0 + tx] = tile[tx][ty + j * 8];
    }
}

// ---------------- GEMM1: qkv = x @ W_qkv + b (permuted N) ------------------------
// X[8192,256] bf16 (pre-converted), Wt[6144,256] bf16 in n' order.
// Double-buffered global_load_lds staging; counted vmcnt(4).
// Q/K: per-wave LDS transpose -> 16B vector stores of dst[bh][t][f] * 1/16.
// V: direct transposed+key-permuted 8B stores.
#define GS 32
__global__ __launch_bounds__(256) void k_gemm_qkv(const __hip_bfloat16* __restrict__ X,
                                                  const __hip_bfloat16* __restrict__ Wt,
                                                  const float* __restrict__ bias,
                                                  __hip_bfloat16* __restrict__ Q,
                                                  __hip_bfloat16* __restrict__ K,
                                                  __hip_bfloat16* __restrict__ Vt) {
    __shared__ __align__(16) short As[2][128 * GS];
    __shared__ __align__(16) short Bs[2][128 * GS];
    const int tid = threadIdx.x;
    const int m0 = blockIdx.y * 128, n0 = blockIdx.x * 128;
    const int w = tid >> 6, lane = tid & 63, l16 = lane & 15, quad = lane >> 4;
    const int wm = (w >> 1) * 64, wn = (w & 1) * 64;

    // staging geometry: chunk ci -> row=ci>>2, col=(ci&3)*8
    const int ci0 = (w * 2 + 0) * 64 + lane, ci1 = (w * 2 + 1) * 64 + lane;
    const int r0s = ci0 >> 2, c0s = (ci0 & 3) * 8;
    const int r1s = ci1 >> 2, c1s = (ci1 & 3) * 8;

    f32x4 acc[4][4];
#pragma unroll
    for (int mi = 0; mi < 4; ++mi)
#pragma unroll
        for (int ni = 0; ni < 4; ++ni) acc[mi][ni] = (f32x4){0.f, 0.f, 0.f, 0.f};

    // prologue: stage k=0 into buffer 0 (4 DMAs per wave)
    dma_lds16(X + (size_t)(m0 + r0s) * 256 + c0s, &As[0][(w * 2 + 0) * 512]);
    dma_lds16(Wt + (size_t)(n0 + r0s) * 256 + c0s, &Bs[0][(w * 2 + 0) * 512]);
    dma_lds16(X + (size_t)(m0 + r1s) * 256 + c1s, &As[0][(w * 2 + 1) * 512]);
    dma_lds16(Wt + (size_t)(n0 + r1s) * 256 + c1s, &Bs[0][(w * 2 + 1) * 512]);

    for (int it = 0; it < 8; ++it) {
        const int cur = it & 1, nxt = cur ^ 1;
        if (it < 7) {
            const int k0 = (it + 1) * 32;
            dma_lds16(X + (size_t)(m0 + r0s) * 256 + k0 + c0s, &As[nxt][(w * 2 + 0) * 512]);
            dma_lds16(Wt + (size_t)(n0 + r0s) * 256 + k0 + c0s, &Bs[nxt][(w * 2 + 0) * 512]);
            dma_lds16(X + (size_t)(m0 + r1s) * 256 + k0 + c1s, &As[nxt][(w * 2 + 1) * 512]);
            dma_lds16(Wt + (size_t)(n0 + r1s) * 256 + k0 + c1s, &Bs[nxt][(w * 2 + 1) * 512]);
            asm volatile("s_waitcnt vmcnt(4)" ::: "memory");  // tile `it` landed
        } else {
            asm volatile("s_waitcnt vmcnt(0)" ::: "memory");
        }
        __builtin_amdgcn_s_barrier();

        bf16x8 af[4], bfr[4];
#pragma unroll
        for (int mi = 0; mi < 4; ++mi)
            af[mi] = *(const bf16x8*)&As[cur][(wm + mi * 16 + l16) * GS + quad * 8];
#pragma unroll
        for (int ni = 0; ni < 4; ++ni)
            bfr[ni] = *(const bf16x8*)&Bs[cur][(wn + ni * 16 + l16) * GS + quad * 8];
#pragma unroll
        for (int mi = 0; mi < 4; ++mi)
#pragma unroll
            for (int ni = 0; ni < 4; ++ni)
                acc[mi][ni] = MFMA16(af[mi], bfr[ni], acc[mi][ni]);

        asm volatile("s_waitcnt lgkmcnt(0)" ::: "memory");  // reads done before overwrite
        __builtin_amdgcn_s_barrier();
    }

    const int c = n0 >> 11;
    if (c < 2) {
        // Q/K epilogue: per-wave LDS transpose (pad-68 rows), then 16B stores.
        __hip_bfloat16* dst = (c == 0) ? Q : K;
        const int h = ((n0 + wn) >> 8) & 7;
        const int fb = (n0 + wn) & 255;
        const int m_base = m0 + wm;
        const int b = m_base >> 11;
        short* ebuf = &As[0][0] + w * (16 * 68);   // 1088 shorts/wave, disjoint
#pragma unroll
        for (int mi = 0; mi < 4; ++mi) {
#pragma unroll
            for (int ni = 0; ni < 4; ++ni) {
                float bv = bias[h * 768 + (fb + ni * 16 + l16) * 3 + c];
#pragma unroll
                for (int r = 0; r < 4; ++r)
                    ebuf[(quad * 4 + r) * 68 + ni * 16 + l16] =
                        bf16_bits((acc[mi][ni][r] + bv) * 0.0625f);
            }
            asm volatile("s_waitcnt lgkmcnt(0)" ::: "memory");
#pragma unroll
            for (int p = 0; p < 2; ++p) {
                int row = p * 8 + (lane >> 3), cc = lane & 7;
                i32x4 v = *(const i32x4*)&ebuf[row * 68 + cc * 8];
                int t = (m_base + mi * 16 + row) & 2047;
                *(i32x4*)(dst + ((size_t)(b * 8 + h) * 2048 + t) * 256 + fb + cc * 8) = v;
            }
            asm volatile("s_waitcnt lgkmcnt(0)" ::: "memory");
        }
    } else {
        // V: Vt[bh][f][(t&~31) | pos], pos = 16(mi&1)+8(quad&1)+4(quad>>1)+r
        const int pos = ((quad & 1) << 3) | ((quad >> 1) << 2);
#pragma unroll
        for (int mi = 0; mi < 4; ++mi) {
            int m = m0 + wm + mi * 16 + quad * 4;  // r = 0
            int b = m >> 11, t = m & 2047;
            size_t tcol = (size_t)(t & ~31) + ((mi & 1) << 4) + pos;
#pragma unroll
            for (int ni = 0; ni < 4; ++ni) {
                int np = n0 + wn + ni * 16 + l16;
                int h = (np >> 8) & 7, f = np & 255;
                float bv = bias[h * 768 + f * 3 + 2];
                s16x4 v;
#pragma unroll
                for (int r = 0; r < 4; ++r) v[r] = bf16_bits(acc[mi][ni][r] + bv);
                *(s16x4*)(Vt + ((size_t)(b * 8 + h) * 256 + f) * 2048 + tcol) = v;
            }
        }
    }
}

// ---------------- flash attention (512 thr, S^T, DMA-K, dbuf, no-shfl P) ---------
// R14 structure + XCD remap + s_setprio around MFMA clusters (R25).
// grid: 256 blocks; xcd=id&7 owns bh in [xcd*4, xcd*4+4); 8 q-blocks of 256.
// Block 512 = 8 waves; wave w owns 32 q-rows (full F=256).
// S^T = K*Q^T: lane owns q=l32 and keys (r&3)+8*(r>>2)+4hi. V stored key-permuted,
// so pf[kk] = pack(exp(s[8kk..8kk+7])) with NO lane exchange.
#define VSS 40
#define ES 40
__global__ __launch_bounds__(512) void k_flash(const __hip_bfloat16* __restrict__ Q,
                                               const __hip_bfloat16* __restrict__ K,
                                               const __hip_bfloat16* __restrict__ Vt,
                                               __hip_bfloat16* __restrict__ O) {
    __shared__ __align__(16) short Ks[2][32 * 256];
    __shared__ __align__(16) short Vs[2][256 * VSS];
    const int tid = threadIdx.x;
    const int w = tid >> 6, lane = tid & 63;
    const int l32 = lane & 31, hi = lane >> 5;

    // XCD-aware remap (index-only; verified FETCH 283->51MB)
    const int id = blockIdx.x;
    const int slot = id >> 3;                  // 0..31 within XCD
    const int bh = (id & 7) * 4 + (slot & 3);  // 4 bh per XCD
    const int q0 = (slot >> 2) * 256;          // 8 q-blocks of 256 rows

    const __hip_bfloat16* Qb = Q + (size_t)bh * 2048 * 256;
    const __hip_bfloat16* Kb = K + (size_t)bh * 2048 * 256;
    const __hip_bfloat16* Vb = Vt + (size_t)bh * 256 * 2048;

    // resident Q fragments (B-operand): lane n=q=l32, k contiguous
    bf16x8 qf[16];
    {
        const __hip_bfloat16* qrow_p = Qb + (size_t)(q0 + w * 32 + l32) * 256 + hi * 8;
#pragma unroll
        for (int kf = 0; kf < 16; ++kf) qf[kf] = *(const bf16x8*)(qrow_p + kf * 16);
    }

    f32x16 oacc[8];
#pragma unroll
    for (int nt = 0; nt < 8; ++nt)
#pragma unroll
        for (int r = 0; r < 16; ++r) oacc[nt][r] = 0.f;
    float lsum = 0.f;

    // staging geometry (512 threads)
    const int vrow = (tid >> 2);            // V rows: p*128 + (tid>>2)
    const int vcol = (tid & 3) * 8;

    // prologue: stage tile 0 into buffer 0
#pragma unroll
    for (int p = 0; p < 2; ++p) {
        int seg = w * 2 + p;
        int r = 2 * seg + hi;
        int clog = l32 ^ (r & 7);
        dma_lds16(Kb + (size_t)r * 256 + clog * 8, &Ks[0][seg * 512]);
    }
#pragma unroll
    for (int p = 0; p < 2; ++p) {
        int row = vrow + p * 128;
        *(i32x4*)&Vs[0][row * VSS + vcol] = *(const i32x4*)(Vb + (size_t)row * 2048 + vcol);
    }
    __syncthreads();

    const int s7 = l32 & 7;
    for (int it = 0; it < 64; ++it) {
        const int cur = it & 1, nxt = cur ^ 1;
        const bool more = it < 63;
        const int ktn = (it + 1) * 32;

        // async K DMA for next tile into alternate buffer + V prefetch to regs
        i32x4 vreg[2];
        if (more) {
#pragma unroll
            for (int p = 0; p < 2; ++p) {
                int seg = w * 2 + p;
                int r = 2 * seg + hi;
                int clog = l32 ^ (r & 7);
                dma_lds16(Kb + (size_t)(ktn + r) * 256 + clog * 8, &Ks[nxt][seg * 512]);
            }
#pragma unroll
            for (int p = 0; p < 2; ++p) {
                int row = vrow + p * 128;
                vreg[p] = *(const i32x4*)(Vb + (size_t)row * 2048 + ktn + vcol);
            }
        }

        // S^T[32key x 32q] = K * Q^T : 16 MFMA over f
        f32x16 s;
#pragma unroll
        for (int r = 0; r < 16; ++r) s[r] = 0.f;
        const short* ksb = &Ks[cur][l32 * 256];
        __builtin_amdgcn_s_setprio(1);
#pragma unroll
        for (int kf = 0; kf < 16; ++kf) {
            int g = kf * 2 + hi;
            bf16x8 kfr = *(const bf16x8*)&ksb[((g ^ s7) * 8)];
            s = MFMA32(kfr, qf[kf], s);
        }
        __builtin_amdgcn_s_setprio(0);

        // per-kk: P = exp(S) packed straight into the B-frag, then PV.
#pragma unroll
        for (int kk = 0; kk < 2; ++kk) {
            unsigned ch[4];
#pragma unroll
            for (int c = 0; c < 4; ++c) {
                float e0 = __expf(s[8 * kk + 2 * c]);
                float e1 = __expf(s[8 * kk + 2 * c + 1]);
                lsum += e0 + e1;
                ch[c] = pack_bf16(e0, e1);
            }
            union { i32x4 i; bf16x8 v; } pf;
            pf.i = (i32x4){(int)ch[0], (int)ch[1], (int)ch[2], (int)ch[3]};

            __builtin_amdgcn_s_setprio(1);
#pragma unroll
            for (int nt = 0; nt < 8; ++nt) {
                bf16x8 vf = *(const bf16x8*)&Vs[cur][(nt * 32 + l32) * VSS + kk * 16 + hi * 8];
                oacc[nt] = MFMA32(vf, pf.v, oacc[nt]);
            }
            __builtin_amdgcn_s_setprio(0);
        }

        if (more) {
#pragma unroll
            for (int p = 0; p < 2; ++p) {
                int row = vrow + p * 128;
                *(i32x4*)&Vs[nxt][row * VSS + vcol] = vreg[p];
            }
        }
        __syncthreads();
    }

    // total row sum: own 16 keys + partner hi-half's 16 keys
    lsum += __shfl_xor(lsum, 32);
    const float inv = 1.f / lsum;

    // epilogue: O^T -> [t][hf] via per-wave LDS transpose (reuse Ks region)
    short* ebuf = &Ks[0][0] + w * (32 * ES);
    const int b = bh >> 3, hh = bh & 7;
#pragma unroll
    for (int nt = 0; nt < 8; ++nt) {
#pragma unroll
        for (int r = 0; r < 16; ++r) {
            int fl = (r & 3) + 8 * (r >> 2) + 4 * hi;
            ebuf[l32 * ES + fl] = bf16_bits(oacc[nt][r] * inv);
        }
        asm volatile("s_waitcnt lgkmcnt(0)" ::: "memory");
#pragma unroll
        for (int p = 0; p < 2; ++p) {
            i32x4 v = *(const i32x4*)&ebuf[(lane >> 1) * ES + (lane & 1) * 8 + p * 16];
            int t = q0 + w * 32 + (lane >> 1);
            __hip_bfloat16* dst =
                O + ((size_t)(b * 2048 + t) * 2048 + hh * 256 + nt * 32 + (lane & 1) * 8 + p * 16);
            *(i32x4*)dst = v;
        }
        asm volatile("s_waitcnt lgkmcnt(0)" ::: "memory");
    }
}

// ---------------- GEMM3: out = attn @ W_proj + b_proj (f32 out) ------------------
// m-tile 64, grid 512 linear (2 blocks/CU). XCD remap: the 4 n-blocks of one
// m-panel run on the SAME XCD. Double-buffered staging, counted vmcnt(2).
__global__ __launch_bounds__(256) void k_gemm_proj(const __hip_bfloat16* __restrict__ A,
                                                   const __hip_bfloat16* __restrict__ Wt,
                                                   const float* __restrict__ bias,
                                                   float* __restrict__ Out) {
    __shared__ __align__(16) short As[2][64 * GS];
    __shared__ __align__(16) short Bs[2][64 * GS];
    const int tid = threadIdx.x;
    const int id = blockIdx.x;
    const int slot = id >> 3;                       // 0..63 within XCD
    const int n0 = (slot & 3) * 64;                 // 4 n-blocks consecutive on one XCD
    const int m0 = ((id & 7) + 8 * (slot >> 2)) * 64;
    const int w = tid >> 6, lane = tid & 63, l16 = lane & 15, quad = lane >> 4;
    const int wm = w * 16;

    // staging: chunk = tid; row = tid>>2 (0..63), col = (tid&3)*8
    const int rS = tid >> 2, cS = (tid & 3) * 8;

    f32x4 acc[4];
#pragma unroll
    for (int ni = 0; ni < 4; ++ni) acc[ni] = (f32x4){0.f, 0.f, 0.f, 0.f};

    // prologue: stage k=0 into buffer 0 (2 DMAs per wave)
    dma_lds16(A + (size_t)(m0 + rS) * 2048 + cS, &As[0][w * 512]);
    dma_lds16(Wt + (size_t)(n0 + rS) * 2048 + cS, &Bs[0][w * 512]);

    for (int it = 0; it < 64; ++it) {
        const int cur = it & 1, nxt = cur ^ 1;
        if (it < 63) {
            const int k0 = (it + 1) * 32;
            dma_lds16(A + (size_t)(m0 + rS) * 2048 + k0 + cS, &As[nxt][w * 512]);
            dma_lds16(Wt + (size_t)(n0 + rS) * 2048 + k0 + cS, &Bs[nxt][w * 512]);
            asm volatile("s_waitcnt vmcnt(2)" ::: "memory");  // tile `it` landed
        } else {
            asm volatile("s_waitcnt vmcnt(0)" ::: "memory");
        }
        __builtin_amdgcn_s_barrier();

        bf16x8 af = *(const bf16x8*)&As[cur][(wm + l16) * GS + quad * 8];
        bf16x8 bfr[4];
#pragma unroll
        for (int ni = 0; ni < 4; ++ni)
            bfr[ni] = *(const bf16x8*)&Bs[cur][(ni * 16 + l16) * GS + quad * 8];
#pragma unroll
        for (int ni = 0; ni < 4; ++ni)
            acc[ni] = MFMA16(af, bfr[ni], acc[ni]);

        asm volatile("s_waitcnt lgkmcnt(0)" ::: "memory");
        __builtin_amdgcn_s_barrier();
    }

#pragma unroll
    for (int ni = 0; ni < 4; ++ni) {
        int n = n0 + ni * 16 + l16;
        float bv = bias[n];
#pragma unroll
        for (int r = 0; r < 4; ++r) {
            int m = m0 + wm + quad * 4 + r;
            Out[(size_t)m * 256 + n] = acc[ni][r] + bv;
        }
    }
}

// ---------------- launch ---------------------------------------------------------
extern "C" void kernel_launch(void* const* d_in, const int* in_sizes, int n_in,
                              void* d_out, int out_size, void* d_ws, size_t ws_size,
                              hipStream_t stream) {
    const float* x      = (const float*)d_in[0];  // [4,2048,256]
    const float* W_qkv  = (const float*)d_in[1];  // [256,6144]
    const float* b_qkv  = (const float*)d_in[2];  // [6144]
    const float* W_proj = (const float*)d_in[3];  // [2048,256]
    const float* b_proj = (const float*)d_in[4];  // [256]
    float* out = (float*)d_out;                   // [4,2048,256]

    const size_t E = 32ull * 2048 * 256;
    __hip_bfloat16* Qb     = (__hip_bfloat16*)d_ws;
    __hip_bfloat16* Kb     = Qb + E;
    __hip_bfloat16* Vt     = Kb + E;
    __hip_bfloat16* attn   = Vt + E;
    __hip_bfloat16* WqkvT  = attn + E;           // 6144*256
    __hip_bfloat16* WprojT = WqkvT + 6144 * 256; // 256*2048
    // Xb aliases attn: gemm_qkv consumes it before k_flash overwrites attn.
    __hip_bfloat16* Xb     = attn;               // 8192*256 bf16 (4 MB of 32 MB)

    k_pre<<<dim3(3072), 256, 0, stream>>>(x, W_qkv, W_proj, Xb, WqkvT, WprojT);
    k_gemm_qkv<<<dim3(48, 64), 256, 0, stream>>>(Xb, WqkvT, b_qkv, Qb, Kb, Vt);
    k_flash<<<dim3(256), 512, 0, stream>>>(Qb, Kb, Vt, attn);
    k_gemm_proj<<<dim3(512), 256, 0, stream>>>(attn, WprojT, b_proj, out);
}